// Round 18
// baseline (44.944 us; speedup 1.0000x reference)
//
#include <hip/hip_runtime.h>
#include <hip/hip_fp16.h>

#define Bdim 4
#define Cdim 128
#define Hdim 96
#define Wdim 96
#define HW   (Hdim*Wdim)        // 9216
#define NOC  18                 // rot conv output channels

typedef __attribute__((ext_vector_type(8))) short bf16x8;
typedef __attribute__((ext_vector_type(4))) float f32x4;
typedef _Float16 h2 __attribute__((ext_vector_type(2)));

__device__ inline short f2bf(float f) {          // round-to-nearest-even bf16
    unsigned u = __float_as_uint(f);
    unsigned r = (u + 0x7FFFu + ((u >> 16) & 1u)) >> 16;
    return (short)r;
}

__device__ inline unsigned pkh2(float a, float b) {   // (b<<16)|a as fp16 pair
    return (unsigned)__half_as_ushort(__float2half(a)) |
           ((unsigned)__half_as_ushort(__float2half(b)) << 16);
}

// ---------------------------------------------------------------------------
// Kernel 1 (prep): x -> bf16 NHWC xnh (halo-padded) + wpk A-fragments +
// packed fp16 weight-quad table wtab. IDENTICAL to R17 (float4 x-reads).
// ---------------------------------------------------------------------------
__global__ __launch_bounds__(256) void prep_kernel(const float* __restrict__ x,
                                                   const float* __restrict__ rot_w,
                                                   const float* __restrict__ weight,
                                                   short* __restrict__ xnh,
                                                   short* __restrict__ wpk,
                                                   uint4* __restrict__ wtab) {
    __shared__ short ldsT[96 * 72];   // [w][c_local], stride 72
    const int bid = blockIdx.x;
    const int t   = threadIdx.x;

    if (bid < 768) {
        int b = bid / 192;
        int h = (bid / 2) % 96;
        int c0 = (bid & 1) * 64;
        const float* xs = x + ((size_t)(b * Cdim + c0) * Hdim + h) * Wdim;
#pragma unroll
        for (int i = 0; i < 6; ++i) {
            int idx = i * 256 + t;           // 0..1535 = 64c x 24 w-quads
            int wq = idx % 24;
            int ci = idx / 24;
            float4 v = *(const float4*)(xs + (size_t)ci * HW + 4 * wq);
            short* dT = &ldsT[(4 * wq) * 72 + ci];
            dT[0]   = f2bf(v.x);
            dT[72]  = f2bf(v.y);
            dT[144] = f2bf(v.z);
            dT[216] = f2bf(v.w);
        }
        __syncthreads();
        short* dst = xnh + (((size_t)b * 98 + (h + 1)) * 98 + 1) * 128 + c0;
#pragma unroll
        for (int j = 0; j < 3; ++j) {
            int idx = j * 256 + t;           // 0..767 = 96w x 8 c-groups
            int c8 = idx % 8;
            int w  = idx / 8;
            *(bf16x8*)(dst + (size_t)w * 128 + c8 * 8) = *(const bf16x8*)&ldsT[w * 72 + c8 * 8];
        }
    } else if (bid < 776) {
        int z = bid - 768;
        int b = z / 2;
        int r = (z & 1) ? 97 : 0;
        short* base = xnh + ((size_t)b * 98 + r) * 98 * 128;
        bf16x8 zero = {0,0,0,0,0,0,0,0};
        for (int i = t; i < 1568; i += 256)      // 1568*8 = 98*128
            ((bf16x8*)base)[i] = zero;
    } else if (bid < 784) {
        int z = bid - 776;
        int b = z / 2;
        int col = (z & 1) ? 97 : 0;
        bf16x8 zero = {0,0,0,0,0,0,0,0};
        for (int i = t; i < 1536; i += 256) {    // rows 1..96 x 16 c-groups
            int r  = 1 + i / 16;
            int c8 = i % 16;
            *(bf16x8*)(xnh + (((size_t)b * 98 + r) * 98 + col) * 128 + c8 * 8) = zero;
        }
    } else if (bid < 928) {
        int f = (bid - 784) * 256 + t;           // 0..36863
        int e    = f & 7;
        int l    = (f >> 3) & 63;
        int ch   = (f >> 9) & 3;
        int tap  = (f >> 11) % 9;
        int mt   = f / 18432;
        int oc = mt * 16 + (l & 15);
        int c  = ch * 32 + (l >> 4) * 8 + e;
        float v = (oc < NOC) ? rot_w[(size_t)oc * (Cdim * 9) + c * 9 + tap] : 0.f;
        wpk[f] = f2bf(v);
    } else {
        for (int i = t; i < 576; i += 256) {
            int e = i >> 6;              // cell 0..8
            int l = i & 63;              // c-pair
            int r = e / 3, s = e % 3;
            const float* w0p = weight + (size_t)(2 * l) * 16;
            uint4 v;
            v.x = pkh2(w0p[r * 4 + s],      w0p[r * 4 + s + 1]);
            v.y = pkh2(w0p[r * 4 + s + 4],  w0p[r * 4 + s + 5]);
            v.z = pkh2(w0p[16 + r * 4 + s],     w0p[16 + r * 4 + s + 1]);
            v.w = pkh2(w0p[16 + r * 4 + s + 4], w0p[16 + r * 4 + s + 5]);
            wtab[i] = v;
        }
    }
}

// ---------------------------------------------------------------------------
// Kernel 2 (FUSED conv+coef+apply). EXACT R15 structure (1 tile/block, 2304
// blocks — R16/R17 proved fewer+longer blocks regress) with two residency
// levers: dsc/ot LDS union (24,064 -> 18,944 B; dsc dead after Phase B, ot
// born late Phase C, barrier between) and __launch_bounds__(256,6) capping
// VGPR at 85 (was 88) -> 6 blocks/CU instead of 5.
// ---------------------------------------------------------------------------
__global__ __launch_bounds__(256, 6) void fused_kernel(const short* __restrict__ xnh,
                                                       const short* __restrict__ wpk,
                                                       const float* __restrict__ rot_b,
                                                       const uint4* __restrict__ wtab,
                                                       float* __restrict__ out) {
    __shared__ uint4 wq4[9][64];     // fp16 weight quads            (9216 B)
    __shared__ union {
        float dsc[4 * 16 * 20];      // conv partials (Phase A/B)    (5120 B)
        float ot[16][130];           // store transpose (Phase C)    (8320 B)
    } scr;                           // union: 8320 B
    __shared__ uint2 cq2[144];       // coef pairs 16px x 9taps      (1152 B)
    __shared__ uint4 lidq[16];       // cell idx bytes [px][16]      ( 256 B)

    const int tid  = threadIdx.x;
    const int lane = tid & 63;
    const int wv   = tid >> 6;       // 0..3

    for (int i = tid; i < 576; i += 256)          // stage weight table once
        ((uint4*)wq4)[i] = wtab[i];

    const int tile = blockIdx.x;                  // 0..2303
    const int b    = tile / 576;
    const int hw0  = (tile % 576) * 16;
    const int h    = hw0 / Wdim;
    const int w0   = hw0 % Wdim;

    // ---- Phase A: conv partials (wave wv = K-chunk wv) ----
    {
        const int px = lane & 15, kg = lane >> 4;
        f32x4 acc0 = {0,0,0,0};      // mt0 rows: oc = kg*4 + r
        f32x4 acc1 = {0,0,0,0};      // mt1 rows: oc = 16 + kg*4 + r
        const short* xb = xnh + (((size_t)b * 98 + h) * 98 + (w0 + px)) * 128
                          + wv * 32 + kg * 8;
        const short* wA = wpk + (size_t)wv * 512 + lane * 8;

        bf16x8 Bc  = *(const bf16x8*)(xb);
        bf16x8 A0c = *(const bf16x8*)(wA);
        bf16x8 A1c = *(const bf16x8*)(wA + 9 * 4 * 512);
#pragma unroll
        for (int tap = 0; tap < 9; ++tap) {
            bf16x8 Bn, A0n, A1n;
            if (tap < 8) {
                const int di = (tap + 1) / 3, dj = (tap + 1) % 3;
                Bn  = *(const bf16x8*)(xb + (di * 98 + dj) * 128);
                A0n = *(const bf16x8*)(wA + (size_t)(tap + 1) * 4 * 512);
                A1n = *(const bf16x8*)(wA + (size_t)(9 + tap + 1) * 4 * 512);
            }
            acc0 = __builtin_amdgcn_mfma_f32_16x16x32_bf16(A0c, Bc, acc0, 0, 0, 0);
            acc1 = __builtin_amdgcn_mfma_f32_16x16x32_bf16(A1c, Bc, acc1, 0, 0, 0);
            if (tap < 8) { Bc = Bn; A0c = A0n; A1c = A1n; }
        }
        float* ds = scr.dsc + ((wv * 16) + px) * 20;
        *(f32x4*)(ds + kg * 4) = acc0;
        if (kg == 0) { ds[16] = acc1[0]; ds[17] = acc1[1]; }
    }
    __syncthreads();

    // ---- Phase B: reduce partials + coefs (tid < 144) ----
    if (tid < 144) {
        const int px = tid / 9;
        const int t9 = tid - px * 9;
        const int i = t9 / 3, j = t9 % 3;
        float ch = rot_b[2 * t9]     + (0.5f + (float)i);
        float cw = rot_b[2 * t9 + 1] + (0.5f + (float)j);
#pragma unroll
        for (int k = 0; k < 4; ++k) {
            const float* ds = scr.dsc + ((k * 16) + px) * 20;
            ch += ds[2 * t9];
            cw += ds[2 * t9 + 1];
        }
        ch = fminf(fmaxf(ch, 0.f), 3.f);
        cw = fminf(fmaxf(cw, 0.f), 3.f);
        float h0f = floorf(ch), w0f = floorf(cw);
        float lh = ch - h0f, lw = cw - w0f;
        int h0 = (int)h0f, w0i = (int)w0f;
        float bh0 = 1.f - lh;
        float aw0 = 1.f - lw;
        if (h0 >= 3)  { h0 = 2;  bh0 = 0.f; }
        if (w0i >= 3) { w0i = 2; aw0 = 0.f; }
        float q00 = aw0 * bh0;
        float q01 = (1.f - aw0) * bh0;
        float q10 = aw0 * (1.f - bh0);
        float q11 = (1.f - aw0) * (1.f - bh0);
        uint2 cf;
        cf.x = pkh2(q00, q01);
        cf.y = pkh2(q10, q11);
        cq2[px * 9 + t9] = cf;
        ((unsigned char*)lidq)[px * 16 + t9] = (unsigned char)(h0 * 3 + w0i);
    }
    __syncthreads();   // after this barrier dsc is dead; ot may reuse the space

    // ---- Phase C: apply (wave wv = px group, lane = c-pair) ----
    const unsigned* xbase =
        (const unsigned*)(xnh + (((size_t)b * 98 + h) * 98 + (w0 + 4 * wv)) * 128) + lane;
    unsigned xw[3][6];
#pragma unroll
    for (int r = 0; r < 3; ++r)
#pragma unroll
        for (int j = 0; j < 6; ++j)
            xw[r][j] = xbase[(r * 98 + j) * 64];

    float acc0[4], acc1[4];
#pragma unroll
    for (int p = 0; p < 4; ++p) { acc0[p] = 0.f; acc1[p] = 0.f; }

#pragma unroll
    for (int pp = 0; pp < 4; ++pp) {
        const int p = 4 * wv + pp;
        uint4 lw = lidq[p];                      // one uniform read -> 9 indices
        uint4 g[9];
        uint2 cf[9];
#pragma unroll
        for (int t = 0; t < 9; ++t) {            // batched independent LDS reads
            unsigned idx = (((const unsigned*)&lw)[t >> 2] >> (8 * (t & 3))) & 0xFu;
            g[t]  = wq4[idx][lane];
            cf[t] = cq2[p * 9 + t];
        }
#pragma unroll
        for (int t = 0; t < 9; ++t) {
            unsigned xu = xw[t / 3][pp + (t % 3)];
            float x0 = __uint_as_float(xu << 16);
            float x1 = __uint_as_float(xu & 0xFFFF0000u);
            float s0 = __builtin_amdgcn_fdot2(__builtin_bit_cast(h2, cf[t].x),
                                              __builtin_bit_cast(h2, g[t].x), 0.f, false);
            s0 = __builtin_amdgcn_fdot2(__builtin_bit_cast(h2, cf[t].y),
                                        __builtin_bit_cast(h2, g[t].y), s0, false);
            float s1 = __builtin_amdgcn_fdot2(__builtin_bit_cast(h2, cf[t].x),
                                              __builtin_bit_cast(h2, g[t].z), 0.f, false);
            s1 = __builtin_amdgcn_fdot2(__builtin_bit_cast(h2, cf[t].y),
                                        __builtin_bit_cast(h2, g[t].w), s1, false);
            acc0[pp] = fmaf(s0, x0, acc0[pp]);
            acc1[pp] = fmaf(s1, x1, acc1[pp]);
        }
    }

    // transpose through LDS (union slot), then coalesced NCHW stores
#pragma unroll
    for (int pp = 0; pp < 4; ++pp)
        *(float2*)&scr.ot[4 * wv + pp][2 * lane] = make_float2(acc0[pp], acc1[pp]);
    __syncthreads();

    const int px = tid & 15;
    const int cr = tid >> 4;                     // 0..15
    float* ob = out + (size_t)b * Cdim * HW + hw0 + px;
#pragma unroll
    for (int k = 0; k < 8; ++k) {
        int ci = cr * 8 + k;
        ob[(size_t)ci * HW] = scr.ot[px][ci];
    }
}

// ---------------------------------------------------------------------------
extern "C" void kernel_launch(void* const* d_in, const int* in_sizes, int n_in,
                              void* d_out, int out_size, void* d_ws, size_t ws_size,
                              hipStream_t stream) {
    const float* x      = (const float*)d_in[0];
    const float* rot_w  = (const float*)d_in[1];
    const float* rot_b  = (const float*)d_in[2];
    const float* weight = (const float*)d_in[3];
    float* out = (float*)d_out;

    char* ws = (char*)d_ws;
    const size_t xnh_bytes = (size_t)Bdim * 98 * 98 * 128 * 2;   // 9,834,496
    const size_t wpk_bytes = (size_t)2 * 9 * 4 * 64 * 8 * 2;     //    73,728

    short* xnh  = (short*)ws;
    short* wpk  = (short*)(ws + xnh_bytes);
    uint4* wtab = (uint4*)(ws + xnh_bytes + wpk_bytes);          // 9,216 B

    prep_kernel<<<929, 256, 0, stream>>>(x, rot_w, weight, xnh, wpk, wtab);
    fused_kernel<<<2304, 256, 0, stream>>>(xnh, wpk, rot_b, wtab, out);
}

// Round 19
// 35.959 us; speedup vs baseline: 1.2499x; 1.2499x over previous
//
#include <hip/hip_runtime.h>
#include <hip/hip_fp16.h>

#define Bdim 4
#define Cdim 128
#define Hdim 96
#define Wdim 96
#define HW   (Hdim*Wdim)        // 9216
#define NOC  18                 // rot conv output channels

typedef __attribute__((ext_vector_type(8))) short bf16x8;
typedef __attribute__((ext_vector_type(4))) float f32x4;
typedef _Float16 h2 __attribute__((ext_vector_type(2)));

__device__ inline short f2bf(float f) {          // round-to-nearest-even bf16
    unsigned u = __float_as_uint(f);
    unsigned r = (u + 0x7FFFu + ((u >> 16) & 1u)) >> 16;
    return (short)r;
}

__device__ inline unsigned pkh2(float a, float b) {   // (b<<16)|a as fp16 pair
    return (unsigned)__half_as_ushort(__float2half(a)) |
           ((unsigned)__half_as_ushort(__float2half(b)) << 16);
}

// ---------------------------------------------------------------------------
// Kernel 1 (prep): x -> bf16 NHWC xnh (halo-padded) + wpk A-fragments +
// packed fp16 weight-quad table wtab. EXACT R15 (scalar x reads — the R17/18
// float4 variant created 16-32-way LDS write conflicts and regressed).
// ---------------------------------------------------------------------------
__global__ __launch_bounds__(256) void prep_kernel(const float* __restrict__ x,
                                                   const float* __restrict__ rot_w,
                                                   const float* __restrict__ weight,
                                                   short* __restrict__ xnh,
                                                   short* __restrict__ wpk,
                                                   uint4* __restrict__ wtab) {
    __shared__ short ldsT[96 * 72];   // [w][c_local], stride 72
    const int bid = blockIdx.x;
    const int t   = threadIdx.x;

    if (bid < 768) {
        int b = bid / 192;
        int h = (bid / 2) % 96;
        int c0 = (bid & 1) * 64;
        const float* xs = x + ((size_t)(b * Cdim + c0) * Hdim + h) * Wdim;
#pragma unroll
        for (int i = 0; i < 24; ++i) {
            int idx = i * 256 + t;           // 0..6143 = 64c x 96w
            int w  = idx % 96;
            int ci = idx / 96;
            ldsT[w * 72 + ci] = f2bf(xs[(size_t)ci * HW + w]);
        }
        __syncthreads();
        short* dst = xnh + (((size_t)b * 98 + (h + 1)) * 98 + 1) * 128 + c0;
#pragma unroll
        for (int j = 0; j < 3; ++j) {
            int idx = j * 256 + t;           // 0..767 = 96w x 8 c-groups
            int c8 = idx % 8;
            int w  = idx / 8;
            *(bf16x8*)(dst + (size_t)w * 128 + c8 * 8) = *(const bf16x8*)&ldsT[w * 72 + c8 * 8];
        }
    } else if (bid < 776) {
        int z = bid - 768;
        int b = z / 2;
        int r = (z & 1) ? 97 : 0;
        short* base = xnh + ((size_t)b * 98 + r) * 98 * 128;
        bf16x8 zero = {0,0,0,0,0,0,0,0};
        for (int i = t; i < 1568; i += 256)      // 1568*8 = 98*128
            ((bf16x8*)base)[i] = zero;
    } else if (bid < 784) {
        int z = bid - 776;
        int b = z / 2;
        int col = (z & 1) ? 97 : 0;
        bf16x8 zero = {0,0,0,0,0,0,0,0};
        for (int i = t; i < 1536; i += 256) {    // rows 1..96 x 16 c-groups
            int r  = 1 + i / 16;
            int c8 = i % 16;
            *(bf16x8*)(xnh + (((size_t)b * 98 + r) * 98 + col) * 128 + c8 * 8) = zero;
        }
    } else if (bid < 928) {
        int f = (bid - 784) * 256 + t;           // 0..36863
        int e    = f & 7;
        int l    = (f >> 3) & 63;
        int ch   = (f >> 9) & 3;
        int tap  = (f >> 11) % 9;
        int mt   = f / 18432;
        int oc = mt * 16 + (l & 15);
        int c  = ch * 32 + (l >> 4) * 8 + e;
        float v = (oc < NOC) ? rot_w[(size_t)oc * (Cdim * 9) + c * 9 + tap] : 0.f;
        wpk[f] = f2bf(v);
    } else {
        for (int i = t; i < 576; i += 256) {
            int e = i >> 6;              // cell 0..8
            int l = i & 63;              // c-pair
            int r = e / 3, s = e % 3;
            const float* w0p = weight + (size_t)(2 * l) * 16;
            uint4 v;
            v.x = pkh2(w0p[r * 4 + s],      w0p[r * 4 + s + 1]);
            v.y = pkh2(w0p[r * 4 + s + 4],  w0p[r * 4 + s + 5]);
            v.z = pkh2(w0p[16 + r * 4 + s],     w0p[16 + r * 4 + s + 1]);
            v.w = pkh2(w0p[16 + r * 4 + s + 4], w0p[16 + r * 4 + s + 5]);
            wtab[i] = v;
        }
    }
}

// ---------------------------------------------------------------------------
// Kernel 2 (FUSED conv+coef+apply). EXACT R15 structure (1 tile/block, 2304
// blocks, no launch_bounds cap — R16/R17/R18 variants all regressed), plus:
//  * dsc/ot LDS union (safe: barrier separates last dsc read / first ot write)
//  * XCD-aware tile swizzle (2304%8==0 -> bijective): each XCD works a
//    contiguous 288-tile chunk whose xnh footprint fits its private L2.
// ---------------------------------------------------------------------------
__global__ __launch_bounds__(256) void fused_kernel(const short* __restrict__ xnh,
                                                    const short* __restrict__ wpk,
                                                    const float* __restrict__ rot_b,
                                                    const uint4* __restrict__ wtab,
                                                    float* __restrict__ out) {
    __shared__ uint4 wq4[9][64];     // fp16 weight quads            (9216 B)
    __shared__ union {
        float dsc[4 * 16 * 20];      // conv partials (Phase A/B)    (5120 B)
        float ot[16][130];           // store transpose (Phase C)    (8320 B)
    } scr;
    __shared__ uint2 cq2[144];       // coef pairs 16px x 9taps      (1152 B)
    __shared__ uint4 lidq[16];       // cell idx bytes [px][16]      ( 256 B)

    const int tid  = threadIdx.x;
    const int lane = tid & 63;
    const int wv   = tid >> 6;       // 0..3

    for (int i = tid; i < 576; i += 256)          // stage weight table once
        ((uint4*)wq4)[i] = wtab[i];

    // XCD swizzle: 2304 tiles, 8 XCDs, 288 contiguous tiles per XCD
    const int tile = (blockIdx.x & 7) * 288 + (blockIdx.x >> 3);
    const int b    = tile / 576;
    const int hw0  = (tile % 576) * 16;
    const int h    = hw0 / Wdim;
    const int w0   = hw0 % Wdim;

    // ---- Phase A: conv partials (wave wv = K-chunk wv) ----
    {
        const int px = lane & 15, kg = lane >> 4;
        f32x4 acc0 = {0,0,0,0};      // mt0 rows: oc = kg*4 + r
        f32x4 acc1 = {0,0,0,0};      // mt1 rows: oc = 16 + kg*4 + r
        const short* xb = xnh + (((size_t)b * 98 + h) * 98 + (w0 + px)) * 128
                          + wv * 32 + kg * 8;
        const short* wA = wpk + (size_t)wv * 512 + lane * 8;

        bf16x8 Bc  = *(const bf16x8*)(xb);
        bf16x8 A0c = *(const bf16x8*)(wA);
        bf16x8 A1c = *(const bf16x8*)(wA + 9 * 4 * 512);
#pragma unroll
        for (int tap = 0; tap < 9; ++tap) {
            bf16x8 Bn, A0n, A1n;
            if (tap < 8) {
                const int di = (tap + 1) / 3, dj = (tap + 1) % 3;
                Bn  = *(const bf16x8*)(xb + (di * 98 + dj) * 128);
                A0n = *(const bf16x8*)(wA + (size_t)(tap + 1) * 4 * 512);
                A1n = *(const bf16x8*)(wA + (size_t)(9 + tap + 1) * 4 * 512);
            }
            acc0 = __builtin_amdgcn_mfma_f32_16x16x32_bf16(A0c, Bc, acc0, 0, 0, 0);
            acc1 = __builtin_amdgcn_mfma_f32_16x16x32_bf16(A1c, Bc, acc1, 0, 0, 0);
            if (tap < 8) { Bc = Bn; A0c = A0n; A1c = A1n; }
        }
        float* ds = scr.dsc + ((wv * 16) + px) * 20;
        *(f32x4*)(ds + kg * 4) = acc0;
        if (kg == 0) { ds[16] = acc1[0]; ds[17] = acc1[1]; }
    }
    __syncthreads();

    // ---- Phase B: reduce partials + coefs (tid < 144) ----
    if (tid < 144) {
        const int px = tid / 9;
        const int t9 = tid - px * 9;
        const int i = t9 / 3, j = t9 % 3;
        float ch = rot_b[2 * t9]     + (0.5f + (float)i);
        float cw = rot_b[2 * t9 + 1] + (0.5f + (float)j);
#pragma unroll
        for (int k = 0; k < 4; ++k) {
            const float* ds = scr.dsc + ((k * 16) + px) * 20;
            ch += ds[2 * t9];
            cw += ds[2 * t9 + 1];
        }
        ch = fminf(fmaxf(ch, 0.f), 3.f);
        cw = fminf(fmaxf(cw, 0.f), 3.f);
        float h0f = floorf(ch), w0f = floorf(cw);
        float lh = ch - h0f, lw = cw - w0f;
        int h0 = (int)h0f, w0i = (int)w0f;
        float bh0 = 1.f - lh;
        float aw0 = 1.f - lw;
        if (h0 >= 3)  { h0 = 2;  bh0 = 0.f; }
        if (w0i >= 3) { w0i = 2; aw0 = 0.f; }
        float q00 = aw0 * bh0;
        float q01 = (1.f - aw0) * bh0;
        float q10 = aw0 * (1.f - bh0);
        float q11 = (1.f - aw0) * (1.f - bh0);
        uint2 cf;
        cf.x = pkh2(q00, q01);
        cf.y = pkh2(q10, q11);
        cq2[px * 9 + t9] = cf;
        ((unsigned char*)lidq)[px * 16 + t9] = (unsigned char)(h0 * 3 + w0i);
    }
    __syncthreads();   // dsc dead after this barrier; ot may reuse the space

    // ---- Phase C: apply (wave wv = px group, lane = c-pair) ----
    const unsigned* xbase =
        (const unsigned*)(xnh + (((size_t)b * 98 + h) * 98 + (w0 + 4 * wv)) * 128) + lane;
    unsigned xw[3][6];
#pragma unroll
    for (int r = 0; r < 3; ++r)
#pragma unroll
        for (int j = 0; j < 6; ++j)
            xw[r][j] = xbase[(r * 98 + j) * 64];

    float acc0[4], acc1[4];
#pragma unroll
    for (int p = 0; p < 4; ++p) { acc0[p] = 0.f; acc1[p] = 0.f; }

#pragma unroll
    for (int pp = 0; pp < 4; ++pp) {
        const int p = 4 * wv + pp;
        uint4 lw = lidq[p];                      // one uniform read -> 9 indices
        uint4 g[9];
        uint2 cf[9];
#pragma unroll
        for (int t = 0; t < 9; ++t) {            // batched independent LDS reads
            unsigned idx = (((const unsigned*)&lw)[t >> 2] >> (8 * (t & 3))) & 0xFu;
            g[t]  = wq4[idx][lane];
            cf[t] = cq2[p * 9 + t];
        }
#pragma unroll
        for (int t = 0; t < 9; ++t) {
            unsigned xu = xw[t / 3][pp + (t % 3)];
            float x0 = __uint_as_float(xu << 16);
            float x1 = __uint_as_float(xu & 0xFFFF0000u);
            float s0 = __builtin_amdgcn_fdot2(__builtin_bit_cast(h2, cf[t].x),
                                              __builtin_bit_cast(h2, g[t].x), 0.f, false);
            s0 = __builtin_amdgcn_fdot2(__builtin_bit_cast(h2, cf[t].y),
                                        __builtin_bit_cast(h2, g[t].y), s0, false);
            float s1 = __builtin_amdgcn_fdot2(__builtin_bit_cast(h2, cf[t].x),
                                              __builtin_bit_cast(h2, g[t].z), 0.f, false);
            s1 = __builtin_amdgcn_fdot2(__builtin_bit_cast(h2, cf[t].y),
                                        __builtin_bit_cast(h2, g[t].w), s1, false);
            acc0[pp] = fmaf(s0, x0, acc0[pp]);
            acc1[pp] = fmaf(s1, x1, acc1[pp]);
        }
    }

    // transpose through LDS (union slot), then coalesced NCHW stores
#pragma unroll
    for (int pp = 0; pp < 4; ++pp)
        *(float2*)&scr.ot[4 * wv + pp][2 * lane] = make_float2(acc0[pp], acc1[pp]);
    __syncthreads();

    const int px = tid & 15;
    const int cr = tid >> 4;                     // 0..15
    float* ob = out + (size_t)b * Cdim * HW + hw0 + px;
#pragma unroll
    for (int k = 0; k < 8; ++k) {
        int ci = cr * 8 + k;
        ob[(size_t)ci * HW] = scr.ot[px][ci];
    }
}

// ---------------------------------------------------------------------------
extern "C" void kernel_launch(void* const* d_in, const int* in_sizes, int n_in,
                              void* d_out, int out_size, void* d_ws, size_t ws_size,
                              hipStream_t stream) {
    const float* x      = (const float*)d_in[0];
    const float* rot_w  = (const float*)d_in[1];
    const float* rot_b  = (const float*)d_in[2];
    const float* weight = (const float*)d_in[3];
    float* out = (float*)d_out;

    char* ws = (char*)d_ws;
    const size_t xnh_bytes = (size_t)Bdim * 98 * 98 * 128 * 2;   // 9,834,496
    const size_t wpk_bytes = (size_t)2 * 9 * 4 * 64 * 8 * 2;     //    73,728

    short* xnh  = (short*)ws;
    short* wpk  = (short*)(ws + xnh_bytes);
    uint4* wtab = (uint4*)(ws + xnh_bytes + wpk_bytes);          // 9,216 B

    prep_kernel<<<929, 256, 0, stream>>>(x, rot_w, weight, xnh, wpk, wtab);
    fused_kernel<<<2304, 256, 0, stream>>>(xnh, wpk, rot_b, wtab, out);
}